// Round 3
// baseline (300.029 us; speedup 1.0000x reference)
//
#include <hip/hip_runtime.h>

// ScaledDotProductAttention: context = softmax(relu(Q K^T) @ R / 8) @ V
// B=8, N=2048, D=64. R = (1+e)/(1+exp(1-dist)), shared across batch.
//
// ws layout (~91.5 MB):
//   [0,   64MB)  Ph  : fp16 relu(QK^T)*0.125, [B][N][N]
//   [64MB,72MB)  RhT : fp16 R^T, [j][m]
//   [72MB,74MB)  VhT : fp16 V^T, [B][64][N]
//   [74MB,90MB)  Op  : fp16 partial O, [512 wg][256][64]
//   [90MB,...)   mp, lp : fp32 partial rowmax/rowsum, [512][256] each

typedef _Float16 f16;
typedef _Float16 f16x8 __attribute__((ext_vector_type(8)));
typedef float    f32x4 __attribute__((ext_vector_type(4)));

#define AS1C(p) ((const __attribute__((address_space(1))) void*)(p))
#define AS3(p)  ((__attribute__((address_space(3))) void*)(p))

__device__ __forceinline__ f16x8 cvt_f16x8(float4 a, float4 b){
  f16x8 v;
  v[0]=(f16)a.x; v[1]=(f16)a.y; v[2]=(f16)a.z; v[3]=(f16)a.w;
  v[4]=(f16)b.x; v[5]=(f16)b.y; v[6]=(f16)b.z; v[7]=(f16)b.w;
  return v;
}

// ---------------- kernel 1: fused prep + QK^T --------------------------------
// Flat grid 3328: [0,2048) QK tiles; [2048,3072) rescale-transpose tiles;
// [3072,3328) V-transpose tiles.
__launch_bounds__(256, 3)
__global__ void k_qk(const float* __restrict__ Q, const float* __restrict__ Km,
                     const float* __restrict__ V, const float* __restrict__ Dm,
                     f16* __restrict__ Ph, f16* __restrict__ RhT,
                     f16* __restrict__ VhT){
  __shared__ __align__(16) char shm[36864];
  const int bid = blockIdx.x;
  const int t = threadIdx.x;

  if (bid >= 2048){
    f16* tl = (f16*)shm;                         // [64][65]
    const int c = t & 63, g = t >> 6;
    if (bid < 3072){                             // RhT[j][m] = rescale(D[m][j])
      const int pid = bid - 2048;
      const int k0 = (pid & 31)*64, m0 = (pid >> 5)*64;
#pragma unroll
      for (int i=0;i<16;++i){
        int k = g*16 + i;
        float d = Dm[(size_t)(k0 + k)*2048 + m0 + c];
        tl[k*65 + c] = (f16)(3.7182818284590452f / (1.0f + __expf(1.0f - d)));
      }
      __syncthreads();
#pragma unroll
      for (int i=0;i<16;++i){
        int m = g*16 + i;
        RhT[(size_t)(m0 + m)*2048 + k0 + c] = tl[c*65 + m];
      }
    } else {                                     // VhT[b][d][m] = V[b][m][d]
      const int pid = bid - 3072;
      const int m0 = (pid & 31)*64, b = pid >> 5;
#pragma unroll
      for (int i=0;i<16;++i){
        int m = g*16 + i;
        tl[m*65 + c] = (f16)V[((size_t)b*2048 + m0 + m)*64 + c];
      }
      __syncthreads();
#pragma unroll
      for (int i=0;i<16;++i){
        int d = g*16 + i;
        VhT[((size_t)b*64 + d)*2048 + m0 + c] = tl[c*65 + d];
      }
    }
    return;
  }

  // ---- QK tile: Ph[128x128] = relu(Q K^T)*0.125 ----
  f16* Qt = (f16*)shm;            // [128][72]
  f16* Kt = (f16*)(shm + 18432);  // [128][72]
  f16* Tt = (f16*)shm;            // [128][136] aliases after compute

  const int w = t>>6, l = t&63, lr = l&15, q = l>>4;
  const int m0 = (bid & 15)*128, n0 = ((bid>>4) & 15)*128, b = bid >> 8;
  const int wr = (w>>1)*64, wc = (w&1)*64;
  const float* Qb = Q  + ((size_t)b*2048 + n0)*64;
  const float* Kb = Km + ((size_t)b*2048 + m0)*64;

  const int sr = t>>3, sc = t&7;
#pragma unroll
  for (int j=0;j<4;++j){
    int row = sr + 32*j;
    const float* p  = Qb + (size_t)row*64 + sc*8;
    *(f16x8*)(Qt + row*72 + sc*8) = cvt_f16x8(*(const float4*)p, *(const float4*)(p+4));
    const float* pk = Kb + (size_t)row*64 + sc*8;
    *(f16x8*)(Kt + row*72 + sc*8) = cvt_f16x8(*(const float4*)pk, *(const float4*)(pk+4));
  }
  __syncthreads();

  f32x4 acc[4][4] = {};
#pragma unroll
  for (int kc=0;kc<2;++kc){
    f16x8 af[4], bf[4];
#pragma unroll
    for (int ti=0;ti<4;++ti) af[ti] = *(const f16x8*)(Qt + (wr+16*ti+lr)*72 + kc*32 + q*8);
#pragma unroll
    for (int tj=0;tj<4;++tj) bf[tj] = *(const f16x8*)(Kt + (wc+16*tj+lr)*72 + kc*32 + q*8);
#pragma unroll
    for (int ti=0;ti<4;++ti)
#pragma unroll
      for (int tj=0;tj<4;++tj)
        acc[ti][tj] = __builtin_amdgcn_mfma_f32_16x16x32_f16(af[ti], bf[tj], acc[ti][tj], 0,0,0);
  }
  __syncthreads();
#pragma unroll
  for (int ti=0;ti<4;++ti)
#pragma unroll
    for (int tj=0;tj<4;++tj)
#pragma unroll
      for (int r=0;r<4;++r)
        Tt[(wr+16*ti+4*q+r)*136 + wc+16*tj+lr] = (f16)(fmaxf(acc[ti][tj][r],0.f)*0.125f);
  __syncthreads();
  const int g16 = t&15, r0 = t>>4;
#pragma unroll
  for (int j=0;j<8;++j){
    int row = r0 + 16*j;
    *(f16x8*)(Ph + ((size_t)b*2048 + n0 + row)*2048 + m0 + g16*8) =
        *(const f16x8*)(Tt + row*136 + g16*8);
  }
}

// ---------------- kernel 2: split-j flash attention, 8-phase schedule -------
// Grid 512 = 8 nb x 8 b x 8 jq; jq = bid&7 == XCD id -> 1MB R-slice L2-resident.
// Per WG: 512 thr = 8 waves, tile 256 rows x 256 j, wave tile 128x64.
// K-loop: 64 tiles of BK=32; triple-buffered LDS (3 x (16KB A + 16KB B) = 96KB,
// 1 WG/CU). Distance-2 prefetch, counted vmcnt(4) ONCE per K-tile (never 0
// until the last tile). Each K-tile = 2 fine phases:
//   { 1 half-stage (2 global_load_lds) | 4-8 ds_read_b128 | s_barrier-paired |
//     lgkmcnt(0) | setprio(1) 16 MFMA setprio(0) }
// Buffer safety: stage(k+2) writes buf (k+2)%3 == (k-1)%3; tile k-1's readers
// finished (per-wave lgkm-complete before reaching tile-k top barrier), and
// the stage issues after that barrier (sched_barrier(0) pins it).
__launch_bounds__(512, 2)
__global__ void k_attn(const f16* __restrict__ Ph, const f16* __restrict__ RhT,
                       const f16* __restrict__ VhT, f16* __restrict__ Op,
                       float* __restrict__ mp, float* __restrict__ lp){
  __shared__ __align__(16) char smem[98304];
  f16* As = (f16*)smem;                      // [3][256][32] f16 (16KB/buf)
  f16* Bs = (f16*)(smem + 49152);            // [3][256][32]
  f16* El = (f16*)smem;                      // [128][264] = 67584 B (alias)
  float* stat_max = (float*)(smem + 67584);  // [128][4] (alias)
  float* stat_sum = (float*)(smem + 69632);  // [128][4] (alias)

  const int t = threadIdx.x, w = t>>6, l = t&63, lr = l&15, q = l>>4;
  const int wr = w>>2, wc2 = w&3;            // wave tile: rows wr*128, cols wc2*64
  const int bid = blockIdx.x;
  const int jq = bid & 7, rbb = bid >> 3, b = rbb & 7, nb = rbb >> 3;
  const int n0 = nb*256, jg = jq*256;

  const f16* Pblk = Ph  + ((size_t)b*2048 + n0)*2048;
  const f16* Vb   = VhT + (size_t)b*64*2048;

  // staging source pointers (pre-swizzled global col-group, m173 pattern)
  const f16* srcA[2];
  const f16* srcB[2];
#pragma unroll
  for (int i=0;i<2;++i){
    int slot = i*512 + t, row = slot>>2, g = slot&3;
    srcA[i] = Pblk + (size_t)row*2048 + (g ^ ((row>>1)&3))*8;
    srcB[i] = RhT + (size_t)(jg + row)*2048 + (g ^ ((row>>1)&3))*8;
  }

  auto stageA = [&](int kt, int sb){
    const int k0 = kt*32;
#pragma unroll
    for (int i=0;i<2;++i)
      __builtin_amdgcn_global_load_lds(AS1C(srcA[i] + k0),
          AS3(As + sb*8192 + i*4096 + w*512), 16, 0, 0);
  };
  auto stageB = [&](int kt, int sb){
    const int k0 = kt*32;
#pragma unroll
    for (int i=0;i<2;++i)
      __builtin_amdgcn_global_load_lds(AS1C(srcB[i] + k0),
          AS3(Bs + sb*8192 + i*4096 + w*512), 16, 0, 0);
  };

  const int swz = (lr>>1)&3;                 // read-side XOR swizzle
  f32x4 acc[8][4] = {};

  stageA(0,0); stageB(0,0);                  // 4 loads (tile 0)
  stageA(1,1); stageB(1,1);                  // 4 loads (tile 1)
  int cur = 0;
  for (int kt = 0; kt < 64; ++kt){
    // top-of-tile: tile kt's 4 loads landed; tile kt+1's 4 stay in flight
    if (kt < 63) asm volatile("s_waitcnt vmcnt(4)" ::: "memory");
    else         asm volatile("s_waitcnt vmcnt(0)" ::: "memory");
    __builtin_amdgcn_s_barrier();
    __builtin_amdgcn_sched_barrier(0);
    int sb = cur + 2; if (sb >= 3) sb -= 3;  // == (kt+2)%3
    const f16* Ab = As + cur*8192;
    const f16* Bb = Bs + cur*8192;

    // ---- phase A: stage A-half of kt+2 | bf[0..3]+af[0..3] | 16 MFMA ----
    if (kt < 62) stageA(kt+2, sb);
    f16x8 bf[4], af[4];
#pragma unroll
    for (int tj=0;tj<4;++tj)
      bf[tj] = *(const f16x8*)(Bb + (wc2*64 + 16*tj + lr)*32 + (q^swz)*8);
#pragma unroll
    for (int ti=0;ti<4;++ti)
      af[ti] = *(const f16x8*)(Ab + (wr*128 + 16*ti + lr)*32 + (q^swz)*8);
    asm volatile("s_waitcnt lgkmcnt(0)" ::: "memory");
    __builtin_amdgcn_sched_barrier(0);
    __builtin_amdgcn_s_setprio(1);
#pragma unroll
    for (int ti=0;ti<4;++ti)
#pragma unroll
      for (int tj=0;tj<4;++tj)
        acc[ti][tj] = __builtin_amdgcn_mfma_f32_16x16x32_f16(af[ti], bf[tj], acc[ti][tj], 0,0,0);
    __builtin_amdgcn_s_setprio(0);
    __builtin_amdgcn_s_barrier();
    __builtin_amdgcn_sched_barrier(0);

    // ---- phase B: stage B-half of kt+2 | af[4..7] | 16 MFMA (bf reused) ----
    if (kt < 62) stageB(kt+2, sb);
#pragma unroll
    for (int ti=0;ti<4;++ti)
      af[ti] = *(const f16x8*)(Ab + (wr*128 + 64 + 16*ti + lr)*32 + (q^swz)*8);
    asm volatile("s_waitcnt lgkmcnt(0)" ::: "memory");
    __builtin_amdgcn_sched_barrier(0);
    __builtin_amdgcn_s_setprio(1);
#pragma unroll
    for (int ti=0;ti<4;++ti)
#pragma unroll
      for (int tj=0;tj<4;++tj)
        acc[4+ti][tj] = __builtin_amdgcn_mfma_f32_16x16x32_f16(af[ti], bf[tj], acc[4+ti][tj], 0,0,0);
    __builtin_amdgcn_s_setprio(0);
    cur += 1; if (cur >= 3) cur -= 3;
  }
  __syncthreads();                           // staging dead; aliases usable

  // ---- softmax + E@V in two 128-row passes (pass p handled by wr==p waves)
#pragma unroll
  for (int p=0;p<2;++p){
    float Mn[8][4];
    if (wr == p){
      float pm[8][4];
#pragma unroll
      for (int ti=0;ti<8;++ti)
#pragma unroll
        for (int r=0;r<4;++r)
          pm[ti][r] = fmaxf(fmaxf(acc[ti][0][r], acc[ti][1][r]),
                            fmaxf(acc[ti][2][r], acc[ti][3][r]));
#pragma unroll
      for (int mm=1;mm<16;mm<<=1)
#pragma unroll
        for (int ti=0;ti<8;++ti)
#pragma unroll
          for (int r=0;r<4;++r)
            pm[ti][r] = fmaxf(pm[ti][r], __shfl_xor(pm[ti][r], mm));
      if (lr == 0)
#pragma unroll
        for (int ti=0;ti<8;++ti)
#pragma unroll
          for (int r=0;r<4;++r)
            stat_max[(16*ti + 4*q + r)*4 + wc2] = pm[ti][r];
    }
    __syncthreads();                         // B1: per-wave maxima visible

    if (wr == p){
      float ps[8][4];
#pragma unroll
      for (int ti=0;ti<8;++ti)
#pragma unroll
        for (int r=0;r<4;++r){
          int row = 16*ti + 4*q + r;
          float4 s4 = *(const float4*)&stat_max[row*4];
          Mn[ti][r] = fmaxf(fmaxf(s4.x,s4.y), fmaxf(s4.z,s4.w));
          ps[ti][r] = 0.f;
        }
#pragma unroll
      for (int ti=0;ti<8;++ti)
#pragma unroll
        for (int tj=0;tj<4;++tj)
#pragma unroll
          for (int r=0;r<4;++r){
            float e = __expf(acc[ti][tj][r] - Mn[ti][r]);
            ps[ti][r] += e;
            El[(16*ti + 4*q + r)*264 + wc2*64 + 16*tj + lr] = (f16)e;
          }
#pragma unroll
      for (int mm=1;mm<16;mm<<=1)
#pragma unroll
        for (int ti=0;ti<8;++ti)
#pragma unroll
          for (int r=0;r<4;++r)
            ps[ti][r] += __shfl_xor(ps[ti][r], mm);
      if (lr == 0)
#pragma unroll
        for (int ti=0;ti<8;++ti)
#pragma unroll
          for (int r=0;r<4;++r)
            stat_sum[(16*ti + 4*q + r)*4 + wc2] = ps[ti][r];
    }
    __syncthreads();                         // B2: El + stat_sum visible

    if (wr == p && wc2 == 0 && lr == 0)
#pragma unroll
      for (int ti=0;ti<8;++ti)
#pragma unroll
        for (int r=0;r<4;++r){
          int row = 16*ti + 4*q + r;
          float4 s4 = *(const float4*)&stat_sum[row*4];
          mp[bid*256 + p*128 + row] = Mn[ti][r];
          lp[bid*256 + p*128 + row] = s4.x + s4.y + s4.z + s4.w;
        }

    // ---- E @ V : all 8 waves; wave w owns rows [w*16, +16) of this pass
    {
      const int er0 = w*16;
      f32x4 Ov[4] = {};
#pragma unroll
      for (int ks=0; ks<8; ++ks){
        f16x8 ae = *(const f16x8*)(El + (er0 + lr)*264 + ks*32 + q*8);
        f16x8 bv[4];
#pragma unroll
        for (int tj2=0;tj2<4;++tj2)
          bv[tj2] = *(const f16x8*)(Vb + (size_t)(16*tj2 + lr)*2048 + jg + ks*32 + q*8);
#pragma unroll
        for (int tj2=0;tj2<4;++tj2)
          Ov[tj2] = __builtin_amdgcn_mfma_f32_16x16x32_f16(ae, bv[tj2], Ov[tj2], 0,0,0);
      }
#pragma unroll
      for (int tj2=0;tj2<4;++tj2)
#pragma unroll
        for (int r=0;r<4;++r)
          Op[((size_t)bid*256 + p*128 + er0 + 4*q + r)*64 + 16*tj2 + lr] = (f16)Ov[tj2][r];
    }
    __syncthreads();                         // B3: El reads done before pass 1
  }
}

// ---------------- kernel 3: combine the 8 j-slice partials -----------------
// Grid 512: rbb = bid>>3 (0..63 row-blocks of 256), qr = bid&7 (32-row chunk).
__global__ void k_comb(const f16* __restrict__ Op, const float* __restrict__ mp,
                       const float* __restrict__ lp, float* __restrict__ out){
  const int rbb = blockIdx.x >> 3;
  const int qr = blockIdx.x & 7;
  const int b = rbb & 7, nb = rbb >> 3;
  const int bid0 = rbb << 3;
  const int t = threadIdx.x;
  const int row = qr*32 + (t >> 3);          // 32 rows x 8 col-groups
  const int c0 = (t & 7)*8;

  float m_[8], a_[8];
  float M = -1e30f, den = 0.f;
#pragma unroll
  for (int i=0;i<8;++i){ m_[i] = mp[(bid0+i)*256 + row]; M = fmaxf(M, m_[i]); }
#pragma unroll
  for (int i=0;i<8;++i){ a_[i] = __expf(m_[i] - M); den += a_[i]*lp[(bid0+i)*256 + row]; }
  float inv = 1.0f / den;

  float o[8] = {};
#pragma unroll
  for (int i=0;i<8;++i){
    f16x8 v = *(const f16x8*)(Op + ((size_t)(bid0+i)*256 + row)*64 + c0);
#pragma unroll
    for (int e=0;e<8;++e) o[e] += a_[i]*(float)v[e];
  }
  float4 o0, o1;
  o0.x=o[0]*inv; o0.y=o[1]*inv; o0.z=o[2]*inv; o0.w=o[3]*inv;
  o1.x=o[4]*inv; o1.y=o[5]*inv; o1.z=o[6]*inv; o1.w=o[7]*inv;
  float* dst = out + ((size_t)b*2048 + nb*256 + row)*64 + c0;
  *(float4*)dst = o0;
  *(float4*)(dst+4) = o1;
}

extern "C" void kernel_launch(void* const* d_in, const int* in_sizes, int n_in,
                              void* d_out, int out_size, void* d_ws, size_t ws_size,
                              hipStream_t stream){
  (void)in_sizes; (void)n_in; (void)out_size; (void)ws_size;
  const float* Q  = (const float*)d_in[0];
  const float* K  = (const float*)d_in[1];
  const float* V  = (const float*)d_in[2];
  const float* Dm = (const float*)d_in[3];
  float* out = (float*)d_out;
  char* ws = (char*)d_ws;
  f16* Ph  = (f16*)ws;                                   // 64 MB
  f16* RhT = (f16*)(ws + (size_t)64*1024*1024);          //  8 MB
  f16* VhT = (f16*)(ws + (size_t)72*1024*1024);          //  2 MB
  f16* Op  = (f16*)(ws + (size_t)74*1024*1024);          // 16 MB (512*256*64 f16)
  float* mpp = (float*)(ws + (size_t)90*1024*1024);      // 512 KB
  float* lpp = mpp + 512*256;                            // 512 KB

  k_qk   <<<dim3(3328), 256, 0, stream>>>(Q, K, V, Dm, Ph, RhT, VhT);
  k_attn <<<dim3(512),  512, 0, stream>>>(Ph, RhT, VhT, Op, mpp, lpp);
  k_comb <<<dim3(512),  256, 0, stream>>>(Op, mpp, lpp, out);
}

// Round 4
// 270.515 us; speedup vs baseline: 1.1091x; 1.1091x over previous
//
#include <hip/hip_runtime.h>

// ScaledDotProductAttention: context = softmax(relu(Q K^T) @ R / 8) @ V
// B=8, N=2048, D=64. R = (1+e)/(1+exp(1-dist)), shared across batch.
//
// ws layout (needs ~91.5 MB):
//   [0,   64MB)  Ph  : fp16 relu(QK^T)*0.125, [B][N][N]
//   [64MB,72MB)  RhT : fp16 R^T, [j][m]
//   [72MB,74MB)  VhT : fp16 V^T, [B][64][N]
//   [74MB,90MB)  Op  : fp16 partial O, [1024 wg][128][64]
//   [90MB,...)   mp, lp : fp32 partial rowmax/rowsum, [1024][128] each

typedef _Float16 f16;
typedef _Float16 f16x8 __attribute__((ext_vector_type(8)));
typedef float    f32x4 __attribute__((ext_vector_type(4)));
typedef float    f32x16 __attribute__((ext_vector_type(16)));

#define AS1C(p) ((const __attribute__((address_space(1))) void*)(p))
#define AS3(p)  ((__attribute__((address_space(3))) void*)(p))

__device__ __forceinline__ f16x8 cvt_f16x8(float4 a, float4 b){
  f16x8 v;
  v[0]=(f16)a.x; v[1]=(f16)a.y; v[2]=(f16)a.z; v[3]=(f16)a.w;
  v[4]=(f16)b.x; v[5]=(f16)b.y; v[6]=(f16)b.z; v[7]=(f16)b.w;
  return v;
}

// ---------------- kernel 1: fused prep + QK^T --------------------------------
// Flat grid 3328: [0,2048) QK tiles; [2048,3072) rescale-transpose tiles;
// [3072,3328) V-transpose tiles. One launch instead of three.
__launch_bounds__(256, 2)
__global__ void k_qk(const float* __restrict__ Q, const float* __restrict__ Km,
                     const float* __restrict__ V, const float* __restrict__ Dm,
                     f16* __restrict__ Ph, f16* __restrict__ RhT,
                     f16* __restrict__ VhT){
  __shared__ __align__(16) char shm[36864];
  const int bid = blockIdx.x;
  const int t = threadIdx.x;

  if (bid >= 2048){
    f16* tl = (f16*)shm;                         // [64][65]
    const int c = t & 63, g = t >> 6;
    if (bid < 3072){                             // RhT[j][m] = rescale(D[m][j])
      const int pid = bid - 2048;
      const int k0 = (pid & 31)*64, m0 = (pid >> 5)*64;
#pragma unroll
      for (int i=0;i<16;++i){
        int k = g*16 + i;
        float d = Dm[(size_t)(k0 + k)*2048 + m0 + c];
        tl[k*65 + c] = (f16)(3.7182818284590452f / (1.0f + __expf(1.0f - d)));
      }
      __syncthreads();
#pragma unroll
      for (int i=0;i<16;++i){
        int m = g*16 + i;
        RhT[(size_t)(m0 + m)*2048 + k0 + c] = tl[c*65 + m];
      }
    } else {                                     // VhT[b][d][m] = V[b][m][d]
      const int pid = bid - 3072;
      const int m0 = (pid & 31)*64, b = pid >> 5;
#pragma unroll
      for (int i=0;i<16;++i){
        int m = g*16 + i;
        tl[m*65 + c] = (f16)V[((size_t)b*2048 + m0 + m)*64 + c];
      }
      __syncthreads();
#pragma unroll
      for (int i=0;i<16;++i){
        int d = g*16 + i;
        VhT[((size_t)b*64 + d)*2048 + m0 + c] = tl[c*65 + d];
      }
    }
    return;
  }

  // ---- QK tile: Ph[128x128] = relu(Q K^T)*0.125 ----
  f16* Qt = (f16*)shm;            // [128][72]
  f16* Kt = (f16*)(shm + 18432);  // [128][72]
  f16* Tt = (f16*)shm;            // [128][136] aliases after compute

  const int w = t>>6, l = t&63, lr = l&15, q = l>>4;
  const int m0 = (bid & 15)*128, n0 = ((bid>>4) & 15)*128, b = bid >> 8;
  const int wr = (w>>1)*64, wc = (w&1)*64;
  const float* Qb = Q  + ((size_t)b*2048 + n0)*64;
  const float* Kb = Km + ((size_t)b*2048 + m0)*64;

  const int sr = t>>3, sc = t&7;
#pragma unroll
  for (int j=0;j<4;++j){
    int row = sr + 32*j;
    const float* p  = Qb + (size_t)row*64 + sc*8;
    *(f16x8*)(Qt + row*72 + sc*8) = cvt_f16x8(*(const float4*)p, *(const float4*)(p+4));
    const float* pk = Kb + (size_t)row*64 + sc*8;
    *(f16x8*)(Kt + row*72 + sc*8) = cvt_f16x8(*(const float4*)pk, *(const float4*)(pk+4));
  }
  __syncthreads();

  f32x4 acc[4][4] = {};
#pragma unroll
  for (int kc=0;kc<2;++kc){
    f16x8 af[4], bf[4];
#pragma unroll
    for (int ti=0;ti<4;++ti) af[ti] = *(const f16x8*)(Qt + (wr+16*ti+lr)*72 + kc*32 + q*8);
#pragma unroll
    for (int tj=0;tj<4;++tj) bf[tj] = *(const f16x8*)(Kt + (wc+16*tj+lr)*72 + kc*32 + q*8);
#pragma unroll
    for (int ti=0;ti<4;++ti)
#pragma unroll
      for (int tj=0;tj<4;++tj)
        acc[ti][tj] = __builtin_amdgcn_mfma_f32_16x16x32_f16(af[ti], bf[tj], acc[ti][tj], 0,0,0);
  }
  __syncthreads();
#pragma unroll
  for (int ti=0;ti<4;++ti)
#pragma unroll
    for (int tj=0;tj<4;++tj)
#pragma unroll
      for (int r=0;r<4;++r)
        Tt[(wr+16*ti+4*q+r)*136 + wc+16*tj+lr] = (f16)(fmaxf(acc[ti][tj][r],0.f)*0.125f);
  __syncthreads();
  const int g16 = t&15, r0 = t>>4;
#pragma unroll
  for (int j=0;j<8;++j){
    int row = r0 + 16*j;
    *(f16x8*)(Ph + ((size_t)b*2048 + n0 + row)*2048 + m0 + g16*8) =
        *(const f16x8*)(Tt + row*136 + g16*8);
  }
}

// ---------------- kernel 2: split-j flash attention over scores ------------
// Round-0 proven structure (1 syncthreads per K-chunk, dbuf global_load_lds),
// S-GEMM switched to v_mfma_f32_32x32x16_f16: per chunk 16 MFMA x ~8 cyc
// (129 cyc) vs 32 x ~4.85 (155 cyc), same LDS bytes, half the MFMA insts.
// A frag (32x16): lane row=l&31, k=(l>>5)*8.. ; C/D: col=lane&31,
// row=(reg&3)+8*(reg>>2)+4*(lane>>5)  [m74/m101-verified layout].
__launch_bounds__(256, 2)
__global__ void k_attn(const f16* __restrict__ Ph, const f16* __restrict__ RhT,
                       const f16* __restrict__ VhT, f16* __restrict__ Op,
                       float* __restrict__ mp, float* __restrict__ lp){
  __shared__ __align__(16) char smem[49152];
  f16*  Pbuf = (f16*)smem;                      // [2][128][32] = 16384
  f16*  Rbuf = (f16*)(smem + 16384);            // [2][256][32] = 32768
  f16*  El   = (f16*)smem;                      // [64][264] = 33792 (alias)
  float* stat_max = (float*)(smem + 33792);     // [64][4] (alias)
  float* stat_sum = (float*)(smem + 34816);     // [64][4] (alias)

  const int t = threadIdx.x, w = t>>6, l = t&63, lr = l&15, q = l>>4;
  const int c31 = l&31, hi = l>>5;
  const int bid = blockIdx.x;
  const int jq = bid & 7, nbb = bid >> 3, b = nbb & 7, nb = nbb >> 3;
  const int n0 = nb*128, jg = jq*256;
  const int wc = w*64;

  const f16* Pblk = Ph  + ((size_t)b*2048 + n0)*2048;
  const f16* Vb   = VhT + (size_t)b*64*2048;

  // hoisted staging source pointers (advance by kc*32 halves each chunk)
  const f16* srcP[2];
  const f16* srcR[4];
#pragma unroll
  for (int i=0;i<2;++i){
    int slot = i*256 + t, row = slot>>2, g = slot&3;
    srcP[i] = Pblk + (size_t)row*2048 + (g ^ ((row>>1)&3))*8;
  }
#pragma unroll
  for (int i=0;i<4;++i){
    int slot = i*256 + t, row = slot>>2, g = slot&3;
    srcR[i] = RhT + (size_t)(jg + row)*2048 + (g ^ ((row>>1)&3))*8;
  }

  auto stage = [&](int kc){
    const int cb = kc & 1, k0 = kc*32;
#pragma unroll
    for (int i=0;i<2;++i)
      __builtin_amdgcn_global_load_lds(AS1C(srcP[i] + k0),
                                       AS3(Pbuf + cb*4096 + i*2048 + w*512), 16, 0, 0);
#pragma unroll
    for (int i=0;i<4;++i)
      __builtin_amdgcn_global_load_lds(AS1C(srcR[i] + k0),
                                       AS3(Rbuf + cb*8192 + i*2048 + w*512), 16, 0, 0);
  };

  const int swz32 = (c31>>1)&3;                 // read-side XOR swizzle key
  f32x16 acc32[4][2] = {};                      // [rowtile 32][coltile 32]
  f32x4 Oacc[2][2][2] = {};

  stage(0);
#pragma unroll 2
  for (int kc = 0; kc < 64; ++kc){
    __syncthreads();                            // chunk kc staged (full drain)
    if (kc < 63) stage(kc+1);
    const int cb = kc & 1;
    const f16* Pb = Pbuf + cb*4096;
    const f16* Rb = Rbuf + cb*8192;
    f16x8 bf[2][2];                             // [ct][kfrag]
#pragma unroll
    for (int ct=0;ct<2;++ct)
#pragma unroll
      for (int f=0;f<2;++f)
        bf[ct][f] = *(const f16x8*)(Rb + (wc + 32*ct + c31)*32 + ((2*f+hi) ^ swz32)*8);
#pragma unroll
    for (int rt=0;rt<4;++rt){
#pragma unroll
      for (int f=0;f<2;++f){
        f16x8 af = *(const f16x8*)(Pb + (32*rt + c31)*32 + ((2*f+hi) ^ swz32)*8);
        acc32[rt][0] = __builtin_amdgcn_mfma_f32_32x32x16_f16(af, bf[0][f], acc32[rt][0], 0,0,0);
        acc32[rt][1] = __builtin_amdgcn_mfma_f32_32x32x16_f16(af, bf[1][f], acc32[rt][1], 0,0,0);
      }
    }
  }
  __syncthreads();                              // staging dead; aliases usable

  // ---- softmax + E@V in two 64-row passes (single epilogue, no running m/l)
  // Pass p covers rowtiles 2p, 2p+1 (local rows u*32 + row32(reg,hi)).
#pragma unroll
  for (int p=0;p<2;++p){
    // ---- row max: per-lane over 2 coltiles, then 32-lane shfl tree ----
    float pm[2][16];
#pragma unroll
    for (int u=0;u<2;++u)
#pragma unroll
      for (int rg=0;rg<16;++rg)
        pm[u][rg] = fmaxf(acc32[2*p+u][0][rg], acc32[2*p+u][1][rg]);
#pragma unroll
    for (int mm=1;mm<32;mm<<=1)
#pragma unroll
      for (int u=0;u<2;++u)
#pragma unroll
        for (int rg=0;rg<16;++rg)
          pm[u][rg] = fmaxf(pm[u][rg], __shfl_xor(pm[u][rg], mm));
    if (c31 == 0)
#pragma unroll
      for (int u=0;u<2;++u)
#pragma unroll
        for (int rg=0;rg<16;++rg){
          int row = u*32 + (rg&3) + 8*(rg>>2) + 4*hi;
          stat_max[row*4 + w] = pm[u][rg];
        }
    __syncthreads();                            // B1: per-wave maxima visible

    float Mn[2][16];
#pragma unroll
    for (int u=0;u<2;++u){
      float ps[16];
#pragma unroll
      for (int rg=0;rg<16;++rg){
        int row = u*32 + (rg&3) + 8*(rg>>2) + 4*hi;
        float4 s4 = *(const float4*)&stat_max[row*4];
        Mn[u][rg] = fmaxf(fmaxf(s4.x,s4.y), fmaxf(s4.z,s4.w));
        ps[rg] = 0.f;
      }
#pragma unroll
      for (int rg=0;rg<16;++rg){
        int row = u*32 + (rg&3) + 8*(rg>>2) + 4*hi;
#pragma unroll
        for (int ct=0;ct<2;++ct){
          float e = __expf(acc32[2*p+u][ct][rg] - Mn[u][rg]);
          ps[rg] += e;
          El[row*264 + wc + ct*32 + c31] = (f16)e;
        }
      }
#pragma unroll
      for (int mm=1;mm<32;mm<<=1)
#pragma unroll
        for (int rg=0;rg<16;++rg)
          ps[rg] += __shfl_xor(ps[rg], mm);
      if (c31 == 0)
#pragma unroll
        for (int rg=0;rg<16;++rg){
          int row = u*32 + (rg&3) + 8*(rg>>2) + 4*hi;
          stat_sum[row*4 + w] = ps[rg];
          if (w == 0) mp[bid*128 + 64*p + row] = Mn[u][rg];  // Mn already global max
        }
    }
    __syncthreads();                            // B2: El + stat_sum visible

    if (w == 0 && c31 == 0)
#pragma unroll
      for (int u=0;u<2;++u)
#pragma unroll
        for (int rg=0;rg<16;++rg){
          int row = u*32 + (rg&3) + 8*(rg>>2) + 4*hi;
          float4 s4 = *(const float4*)&stat_sum[row*4];
          lp[bid*128 + 64*p + row] = s4.x + s4.y + s4.z + s4.w;
        }

    // ---- E @ V : O[pass rows][cols] += E[64][256] * V[256][64] (16x16x32)
    const int erb = 32*(w&1), vcb = 32*(w>>1);
#pragma unroll
    for (int ks=0; ks<8; ++ks){
      f16x8 ae[2], bv[2];
#pragma unroll
      for (int a=0;a<2;++a)
        ae[a] = *(const f16x8*)(El + (erb + 16*a + lr)*264 + ks*32 + q*8);
#pragma unroll
      for (int bb=0;bb<2;++bb)
        bv[bb] = *(const f16x8*)(Vb + (size_t)(vcb + 16*bb + lr)*2048 + jg + ks*32 + q*8);
#pragma unroll
      for (int a=0;a<2;++a)
#pragma unroll
        for (int bb=0;bb<2;++bb)
          Oacc[p][a][bb] = __builtin_amdgcn_mfma_f32_16x16x32_f16(ae[a], bv[bb], Oacc[p][a][bb], 0,0,0);
    }
    __syncthreads();                            // B3: El reads done before pass 1
  }

#pragma unroll
  for (int p=0;p<2;++p)
#pragma unroll
    for (int a=0;a<2;++a)
#pragma unroll
      for (int bb=0;bb<2;++bb)
#pragma unroll
        for (int r=0;r<4;++r){
          int row = 64*p + 32*(w&1) + 16*a + 4*q + r;
          int col = 32*(w>>1) + 16*bb + lr;
          Op[((size_t)bid*128 + row)*64 + col] = (f16)Oacc[p][a][bb][r];
        }
}

// ---------------- kernel 3: combine the 8 j-slice partials -----------------
// Grid 512: 32 rows per WG so all CUs have work.
__global__ void k_comb(const f16* __restrict__ Op, const float* __restrict__ mp,
                       const float* __restrict__ lp, float* __restrict__ out){
  const int rb = blockIdx.x >> 2;               // 0..127 = nb*8 + b
  const int qr = blockIdx.x & 3;                // row quarter
  const int b = rb & 7, nb = rb >> 3;
  const int bid0 = rb << 3;
  const int t = threadIdx.x;
  const int row = qr*32 + (t >> 3);             // 32 rows x 8 col-groups
  const int c0 = (t & 7)*8;

  float m_[8], a_[8];
  float M = -1e30f, den = 0.f;
#pragma unroll
  for (int i=0;i<8;++i){ m_[i] = mp[(bid0+i)*128 + row]; M = fmaxf(M, m_[i]); }
#pragma unroll
  for (int i=0;i<8;++i){ a_[i] = __expf(m_[i] - M); den += a_[i]*lp[(bid0+i)*128 + row]; }
  float inv = 1.0f / den;

  float o[8] = {};
#pragma unroll
  for (int i=0;i<8;++i){
    f16x8 v = *(const f16x8*)(Op + ((size_t)(bid0+i)*128 + row)*64 + c0);
#pragma unroll
    for (int e=0;e<8;++e) o[e] += a_[i]*(float)v[e];
  }
  float4 o0, o1;
  o0.x=o[0]*inv; o0.y=o[1]*inv; o0.z=o[2]*inv; o0.w=o[3]*inv;
  o1.x=o[4]*inv; o1.y=o[5]*inv; o1.z=o[6]*inv; o1.w=o[7]*inv;
  float* dst = out + ((size_t)b*2048 + nb*128 + row)*64 + c0;
  *(float4*)dst = o0;
  *(float4*)(dst+4) = o1;
}

extern "C" void kernel_launch(void* const* d_in, const int* in_sizes, int n_in,
                              void* d_out, int out_size, void* d_ws, size_t ws_size,
                              hipStream_t stream){
  (void)in_sizes; (void)n_in; (void)out_size; (void)ws_size;
  const float* Q  = (const float*)d_in[0];
  const float* K  = (const float*)d_in[1];
  const float* V  = (const float*)d_in[2];
  const float* Dm = (const float*)d_in[3];
  float* out = (float*)d_out;
  char* ws = (char*)d_ws;
  f16* Ph  = (f16*)ws;                                   // 64 MB
  f16* RhT = (f16*)(ws + (size_t)64*1024*1024);          //  8 MB
  f16* VhT = (f16*)(ws + (size_t)72*1024*1024);          //  2 MB
  f16* Op  = (f16*)(ws + (size_t)74*1024*1024);          // 16 MB (1024*128*64 f16)
  float* mpp = (float*)(ws + (size_t)90*1024*1024);      // 512 KB
  float* lpp = mpp + 1024*128;                           // 512 KB

  k_qk   <<<dim3(3328), 256, 0, stream>>>(Q, K, V, Dm, Ph, RhT, VhT);
  k_attn <<<dim3(1024), 256, 0, stream>>>(Ph, RhT, VhT, Op, mpp, lpp);
  k_comb <<<dim3(512),  256, 0, stream>>>(Op, mpp, lpp, out);
}

// Round 5
// 236.132 us; speedup vs baseline: 1.2706x; 1.1456x over previous
//
#include <hip/hip_runtime.h>

// ScaledDotProductAttention: context = softmax(relu(Q K^T) @ R / 8) @ V
// B=8, N=2048, D=64. R = (1+e)/(1+exp(1-dist)), shared across batch.
//
// ws layout (needs ~91.5 MB):
//   [0,   64MB)  Ph  : fp16 relu(QK^T)*0.125, [B][N][N]
//   [64MB,72MB)  RhT : fp16 R^T, [j][m]
//   [72MB,74MB)  VhT : fp16 V^T, [B][64][N]
//   [74MB,90MB)  Op  : fp16 partial O, [1024 wg][128][64]
//   [90MB,...)   mp, lp : fp32 partial rowmax/rowsum, [1024][128] each

typedef _Float16 f16;
typedef _Float16 f16x8 __attribute__((ext_vector_type(8)));
typedef float    f32x4 __attribute__((ext_vector_type(4)));

#define AS1C(p) ((const __attribute__((address_space(1))) void*)(p))
#define AS3(p)  ((__attribute__((address_space(3))) void*)(p))

__device__ __forceinline__ f16x8 cvt_f16x8(float4 a, float4 b){
  f16x8 v;
  v[0]=(f16)a.x; v[1]=(f16)a.y; v[2]=(f16)a.z; v[3]=(f16)a.w;
  v[4]=(f16)b.x; v[5]=(f16)b.y; v[6]=(f16)b.z; v[7]=(f16)b.w;
  return v;
}

// ---------------- kernel 1: fused prep + QK^T --------------------------------
// Flat grid 3328: [0,2048) QK tiles; [2048,3072) rescale-transpose tiles;
// [3072,3328) V-transpose tiles. One launch instead of three.
__launch_bounds__(256, 2)
__global__ void k_qk(const float* __restrict__ Q, const float* __restrict__ Km,
                     const float* __restrict__ V, const float* __restrict__ Dm,
                     f16* __restrict__ Ph, f16* __restrict__ RhT,
                     f16* __restrict__ VhT){
  __shared__ __align__(16) char shm[36864];
  const int bid = blockIdx.x;
  const int t = threadIdx.x;

  if (bid >= 2048){
    f16* tl = (f16*)shm;                         // [64][65]
    const int c = t & 63, g = t >> 6;
    if (bid < 3072){                             // RhT[j][m] = rescale(D[m][j])
      const int pid = bid - 2048;
      const int k0 = (pid & 31)*64, m0 = (pid >> 5)*64;
#pragma unroll
      for (int i=0;i<16;++i){
        int k = g*16 + i;
        float d = Dm[(size_t)(k0 + k)*2048 + m0 + c];
        tl[k*65 + c] = (f16)(3.7182818284590452f / (1.0f + __expf(1.0f - d)));
      }
      __syncthreads();
#pragma unroll
      for (int i=0;i<16;++i){
        int m = g*16 + i;
        RhT[(size_t)(m0 + m)*2048 + k0 + c] = tl[c*65 + m];
      }
    } else {                                     // VhT[b][d][m] = V[b][m][d]
      const int pid = bid - 3072;
      const int m0 = (pid & 31)*64, b = pid >> 5;
#pragma unroll
      for (int i=0;i<16;++i){
        int m = g*16 + i;
        tl[m*65 + c] = (f16)V[((size_t)b*2048 + m0 + m)*64 + c];
      }
      __syncthreads();
#pragma unroll
      for (int i=0;i<16;++i){
        int d = g*16 + i;
        VhT[((size_t)b*64 + d)*2048 + m0 + c] = tl[c*65 + d];
      }
    }
    return;
  }

  // ---- QK tile: Ph[128x128] = relu(Q K^T)*0.125 ----
  f16* Qt = (f16*)shm;            // [128][72]
  f16* Kt = (f16*)(shm + 18432);  // [128][72]
  f16* Tt = (f16*)shm;            // [128][136] aliases after compute

  const int w = t>>6, l = t&63, lr = l&15, q = l>>4;
  const int m0 = (bid & 15)*128, n0 = ((bid>>4) & 15)*128, b = bid >> 8;
  const int wr = (w>>1)*64, wc = (w&1)*64;
  const float* Qb = Q  + ((size_t)b*2048 + n0)*64;
  const float* Kb = Km + ((size_t)b*2048 + m0)*64;

  const int sr = t>>3, sc = t&7;
#pragma unroll
  for (int j=0;j<4;++j){
    int row = sr + 32*j;
    const float* p  = Qb + (size_t)row*64 + sc*8;
    *(f16x8*)(Qt + row*72 + sc*8) = cvt_f16x8(*(const float4*)p, *(const float4*)(p+4));
    const float* pk = Kb + (size_t)row*64 + sc*8;
    *(f16x8*)(Kt + row*72 + sc*8) = cvt_f16x8(*(const float4*)pk, *(const float4*)(pk+4));
  }
  __syncthreads();

  f32x4 acc[4][4] = {};
#pragma unroll
  for (int kc=0;kc<2;++kc){
    f16x8 af[4], bf[4];
#pragma unroll
    for (int ti=0;ti<4;++ti) af[ti] = *(const f16x8*)(Qt + (wr+16*ti+lr)*72 + kc*32 + q*8);
#pragma unroll
    for (int tj=0;tj<4;++tj) bf[tj] = *(const f16x8*)(Kt + (wc+16*tj+lr)*72 + kc*32 + q*8);
#pragma unroll
    for (int ti=0;ti<4;++ti)
#pragma unroll
      for (int tj=0;tj<4;++tj)
        acc[ti][tj] = __builtin_amdgcn_mfma_f32_16x16x32_f16(af[ti], bf[tj], acc[ti][tj], 0,0,0);
  }
  __syncthreads();
#pragma unroll
  for (int ti=0;ti<4;++ti)
#pragma unroll
    for (int tj=0;tj<4;++tj)
#pragma unroll
      for (int r=0;r<4;++r)
        Tt[(wr+16*ti+4*q+r)*136 + wc+16*tj+lr] = (f16)(fmaxf(acc[ti][tj][r],0.f)*0.125f);
  __syncthreads();
  const int g16 = t&15, r0 = t>>4;
#pragma unroll
  for (int j=0;j<8;++j){
    int row = r0 + 16*j;
    *(f16x8*)(Ph + ((size_t)b*2048 + n0 + row)*2048 + m0 + g16*8) =
        *(const f16x8*)(Tt + row*136 + g16*8);
  }
}

// ---------------- kernel 2: split-j flash attention over scores ------------
// Round-0 proven body. NEW decode: b=bid&7, jq=(bid>>3)&7, nb=bid>>6.
//   XCD = bid%8 = b  -> per XCD: one batch; V-slice (256KB) L2-resident.
//   Co-resident ~64 WGs/XCD = {8 nb} x {8 jq}: each Ph chunk (8KB) shared 8x
//   across jq IN-L2; each R chunk (16KB) shared 8x across nb IN-L2.
//   Goal: stage() loads become L2 hits -> the vmcnt(0) serial-latency stall
//   (the known ~40% of this structure) collapses toward chunk-compute time.
// Per WG (256 thr): 128 Q-rows x ONE 256-col j-tile; per m-chunk(32):
// stage P 8K + R 16K via swizzled global_load_lds (dbuf); wave tile 128x64.
__launch_bounds__(256, 2)
__global__ void k_attn(const f16* __restrict__ Ph, const f16* __restrict__ RhT,
                       const f16* __restrict__ VhT, f16* __restrict__ Op,
                       float* __restrict__ mp, float* __restrict__ lp){
  __shared__ __align__(16) char smem[49152];
  f16*  Pbuf = (f16*)smem;                      // [2][128][32] = 16384
  f16*  Rbuf = (f16*)(smem + 16384);            // [2][256][32] = 32768
  f16*  El   = (f16*)smem;                      // [64][264] = 33792 (alias)
  float* stat_max = (float*)(smem + 33792);     // [64][4] = 1024 (alias)
  float* stat_sum = (float*)(smem + 34816);     // [64][4] = 1024 (alias)

  const int t = threadIdx.x, w = t>>6, l = t&63, lr = l&15, q = l>>4;
  const int bid = blockIdx.x;
  const int b = bid & 7, jq = (bid >> 3) & 7, nb = bid >> 6;
  const int n0 = nb*128, jg = jq*256;
  const int wc = w*64;

  const f16* Pblk = Ph  + ((size_t)b*2048 + n0)*2048;
  const f16* Vb   = VhT + (size_t)b*64*2048;

  // hoisted staging source pointers (advance by kc*32 halves each chunk)
  const f16* srcP[2];
  const f16* srcR[4];
#pragma unroll
  for (int i=0;i<2;++i){
    int slot = i*256 + t, row = slot>>2, g = slot&3;
    srcP[i] = Pblk + (size_t)row*2048 + (g ^ ((row>>1)&3))*8;
  }
#pragma unroll
  for (int i=0;i<4;++i){
    int slot = i*256 + t, row = slot>>2, g = slot&3;
    srcR[i] = RhT + (size_t)(jg + row)*2048 + (g ^ ((row>>1)&3))*8;
  }

  auto stage = [&](int kc){
    const int cb = kc & 1, k0 = kc*32;
#pragma unroll
    for (int i=0;i<2;++i)
      __builtin_amdgcn_global_load_lds(AS1C(srcP[i] + k0),
                                       AS3(Pbuf + cb*4096 + i*2048 + w*512), 16, 0, 0);
#pragma unroll
    for (int i=0;i<4;++i)
      __builtin_amdgcn_global_load_lds(AS1C(srcR[i] + k0),
                                       AS3(Rbuf + cb*8192 + i*2048 + w*512), 16, 0, 0);
  };

  const int swz = (lr>>1)&3;                    // read-side XOR swizzle
  f32x4 acc[8][4] = {};
  f32x4 Oacc[2][2][2] = {};

  stage(0);
#pragma unroll 2
  for (int kc = 0; kc < 64; ++kc){
    __syncthreads();                            // chunk kc staged
    if (kc < 63) stage(kc+1);
    const int cb = kc & 1;
    const f16* Pb = Pbuf + cb*4096;
    const f16* Rb = Rbuf + cb*8192;
    f16x8 bf[4];
#pragma unroll
    for (int tj=0;tj<4;++tj)
      bf[tj] = *(const f16x8*)(Rb + (wc + 16*tj + lr)*32 + (q ^ swz)*8);
#pragma unroll
    for (int ti=0;ti<8;++ti){
      f16x8 af = *(const f16x8*)(Pb + (16*ti + lr)*32 + (q ^ swz)*8);
#pragma unroll
      for (int tj=0;tj<4;++tj)
        acc[ti][tj] = __builtin_amdgcn_mfma_f32_16x16x32_f16(af, bf[tj], acc[ti][tj], 0,0,0);
    }
  }
  __syncthreads();                              // staging dead; aliases usable

  // ---- softmax + E@V in two 64-row passes (single epilogue, no running m/l)
#pragma unroll
  for (int p=0;p<2;++p){
    float pm[4][4];
#pragma unroll
    for (int ti=0;ti<4;++ti)
#pragma unroll
      for (int r=0;r<4;++r)
        pm[ti][r] = fmaxf(fmaxf(acc[4*p+ti][0][r], acc[4*p+ti][1][r]),
                          fmaxf(acc[4*p+ti][2][r], acc[4*p+ti][3][r]));
#pragma unroll
    for (int mm=1;mm<16;mm<<=1)
#pragma unroll
      for (int ti=0;ti<4;++ti)
#pragma unroll
        for (int r=0;r<4;++r)
          pm[ti][r] = fmaxf(pm[ti][r], __shfl_xor(pm[ti][r], mm));
    if (lr == 0)
#pragma unroll
      for (int ti=0;ti<4;++ti)
#pragma unroll
        for (int r=0;r<4;++r)
          stat_max[(16*ti + 4*q + r)*4 + w] = pm[ti][r];
    __syncthreads();                            // B1: per-wave maxima visible

    float Mn[4][4], ps[4][4];
#pragma unroll
    for (int ti=0;ti<4;++ti)
#pragma unroll
      for (int r=0;r<4;++r){
        int row = 16*ti + 4*q + r;
        float4 s4 = *(const float4*)&stat_max[row*4];
        Mn[ti][r] = fmaxf(fmaxf(s4.x,s4.y), fmaxf(s4.z,s4.w));
        ps[ti][r] = 0.f;
      }
#pragma unroll
    for (int ti=0;ti<4;++ti)
#pragma unroll
      for (int tj=0;tj<4;++tj)
#pragma unroll
        for (int r=0;r<4;++r){
          float e = __expf(acc[4*p+ti][tj][r] - Mn[ti][r]);
          ps[ti][r] += e;
          El[(16*ti + 4*q + r)*264 + wc + 16*tj + lr] = (f16)e;
        }
#pragma unroll
    for (int mm=1;mm<16;mm<<=1)
#pragma unroll
      for (int ti=0;ti<4;++ti)
#pragma unroll
        for (int r=0;r<4;++r)
          ps[ti][r] += __shfl_xor(ps[ti][r], mm);
    if (lr == 0)
#pragma unroll
      for (int ti=0;ti<4;++ti)
#pragma unroll
        for (int r=0;r<4;++r)
          stat_sum[(16*ti + 4*q + r)*4 + w] = ps[ti][r];
    __syncthreads();                            // B2: El + stat_sum visible

    if (w == 0 && lr == 0)                      // write per-row max/sum
#pragma unroll
      for (int ti=0;ti<4;++ti)
#pragma unroll
        for (int r=0;r<4;++r){
          int row = 16*ti + 4*q + r;
          float4 s4 = *(const float4*)&stat_sum[row*4];
          mp[bid*128 + 64*p + row] = Mn[ti][r];
          lp[bid*128 + 64*p + row] = s4.x + s4.y + s4.z + s4.w;
        }

    // ---- E @ V : O[pass rows][cols] += E[64][256] * V[256][64]
    const int erb = 32*(w&1), vcb = 32*(w>>1);
#pragma unroll
    for (int ks=0; ks<8; ++ks){
      f16x8 ae[2], bv[2];
#pragma unroll
      for (int a=0;a<2;++a)
        ae[a] = *(const f16x8*)(El + (erb + 16*a + lr)*264 + ks*32 + q*8);
#pragma unroll
      for (int bb=0;bb<2;++bb)
        bv[bb] = *(const f16x8*)(Vb + (size_t)(vcb + 16*bb + lr)*2048 + jg + ks*32 + q*8);
#pragma unroll
      for (int a=0;a<2;++a)
#pragma unroll
        for (int bb=0;bb<2;++bb)
          Oacc[p][a][bb] = __builtin_amdgcn_mfma_f32_16x16x32_f16(ae[a], bv[bb], Oacc[p][a][bb], 0,0,0);
    }
    __syncthreads();                            // B3: El reads done before pass 1
  }

#pragma unroll
  for (int p=0;p<2;++p)
#pragma unroll
    for (int a=0;a<2;++a)
#pragma unroll
      for (int bb=0;bb<2;++bb)
#pragma unroll
        for (int r=0;r<4;++r){
          int row = 64*p + 32*(w&1) + 16*a + 4*q + r;
          int col = 32*(w>>1) + 16*bb + lr;
          Op[((size_t)bid*128 + row)*64 + col] = (f16)Oacc[p][a][bb][r];
        }
}

// ---------------- kernel 3: combine the 8 j-slice partials -----------------
// Grid 512: 32 rows per WG so all CUs have work. Partial i for output block
// (nb,b) lives at k_attn bid = nb*64 + i*8 + b (matches new k_attn decode).
__global__ void k_comb(const f16* __restrict__ Op, const float* __restrict__ mp,
                       const float* __restrict__ lp, float* __restrict__ out){
  const int rb = blockIdx.x >> 2;               // 0..127 = nb*8 + b
  const int qr = blockIdx.x & 3;                // row quarter
  const int b = rb & 7, nb = rb >> 3;
  const int pb = nb*64 + b;                     // partial i at pb + i*8
  const int t = threadIdx.x;
  const int row = qr*32 + (t >> 3);             // 32 rows x 8 col-groups
  const int c0 = (t & 7)*8;

  float m_[8], a_[8];
  float M = -1e30f, den = 0.f;
#pragma unroll
  for (int i=0;i<8;++i){ m_[i] = mp[(pb + i*8)*128 + row]; M = fmaxf(M, m_[i]); }
#pragma unroll
  for (int i=0;i<8;++i){ a_[i] = __expf(m_[i] - M); den += a_[i]*lp[(pb + i*8)*128 + row]; }
  float inv = 1.0f / den;

  float o[8] = {};
#pragma unroll
  for (int i=0;i<8;++i){
    f16x8 v = *(const f16x8*)(Op + ((size_t)(pb + i*8)*128 + row)*64 + c0);
#pragma unroll
    for (int e=0;e<8;++e) o[e] += a_[i]*(float)v[e];
  }
  float4 o0, o1;
  o0.x=o[0]*inv; o0.y=o[1]*inv; o0.z=o[2]*inv; o0.w=o[3]*inv;
  o1.x=o[4]*inv; o1.y=o[5]*inv; o1.z=o[6]*inv; o1.w=o[7]*inv;
  float* dst = out + ((size_t)b*2048 + nb*128 + row)*64 + c0;
  *(float4*)dst = o0;
  *(float4*)(dst+4) = o1;
}

extern "C" void kernel_launch(void* const* d_in, const int* in_sizes, int n_in,
                              void* d_out, int out_size, void* d_ws, size_t ws_size,
                              hipStream_t stream){
  (void)in_sizes; (void)n_in; (void)out_size; (void)ws_size;
  const float* Q  = (const float*)d_in[0];
  const float* K  = (const float*)d_in[1];
  const float* V  = (const float*)d_in[2];
  const float* Dm = (const float*)d_in[3];
  float* out = (float*)d_out;
  char* ws = (char*)d_ws;
  f16* Ph  = (f16*)ws;                                   // 64 MB
  f16* RhT = (f16*)(ws + (size_t)64*1024*1024);          //  8 MB
  f16* VhT = (f16*)(ws + (size_t)72*1024*1024);          //  2 MB
  f16* Op  = (f16*)(ws + (size_t)74*1024*1024);          // 16 MB (1024*128*64 f16)
  float* mpp = (float*)(ws + (size_t)90*1024*1024);      // 512 KB
  float* lpp = mpp + 1024*128;                           // 512 KB

  k_qk   <<<dim3(3328), 256, 0, stream>>>(Q, K, V, Dm, Ph, RhT, VhT);
  k_attn <<<dim3(1024), 256, 0, stream>>>(Ph, RhT, VhT, Op, mpp, lpp);
  k_comb <<<dim3(512),  256, 0, stream>>>(Op, mpp, lpp, out);
}